// Round 7
// baseline (1354.124 us; speedup 1.0000x reference)
//
#include <hip/hip_runtime.h>

#define NS 262144
#define NK 27

typedef float f32x4 __attribute__((ext_vector_type(4)));
typedef __bf16 bf16x8 __attribute__((ext_vector_type(8)));

__device__ __forceinline__ unsigned short f2bf(float f) {
  union { float f; unsigned int i; } c; c.f = f;
  unsigned int r = c.i + 0x7fffu + ((c.i >> 16) & 1u);
  return (unsigned short)(r >> 16);
}
__device__ __forceinline__ float bf2f(unsigned short u) {
  union { unsigned int i; float f; } c; c.i = ((unsigned int)u) << 16;
  return c.f;
}
__device__ __forceinline__ void async16(const void* gp, void* lp) {
  __builtin_amdgcn_global_load_lds((const __attribute__((address_space(1))) void*)gp,
                                   (__attribute__((address_space(3))) void*)lp, 16, 0, 0);
}

// ---------------- prep: idx2_t[k][site] = mask ? idx : NS (zero-row sentinel) ----------
__global__ __launch_bounds__(256) void prep_idx_kernel(const int* __restrict__ nidx,
                                                       const int* __restrict__ nmask,
                                                       int* __restrict__ idx2t) {
  __shared__ int li[256 * NK];
  __shared__ int lm[256 * NK];
  const int t = threadIdx.x;
  const int sb = blockIdx.x * 256;
  for (int j = t; j < 256 * NK; j += 256) {
    li[j] = nidx[(size_t)sb * NK + j];
    lm[j] = nmask[(size_t)sb * NK + j];
  }
  __syncthreads();
  for (int k = 0; k < NK; ++k) {
    int m = lm[t * NK + k];
    int v = li[t * NK + k];
    idx2t[(size_t)k * NS + sb + t] = m ? v : NS;
  }
}

// ---------------- prep: W[k][cin][cout] fp32 -> Wt[k][cout][cin] bf16 ------------------
__global__ __launch_bounds__(256) void prep_w_kernel(const float* __restrict__ W1,
                                                     const float* __restrict__ W2,
                                                     unsigned short* __restrict__ Wt1,
                                                     unsigned short* __restrict__ Wt2) {
  const int b = blockIdx.x;  // 0..53
  const float* W = (b < NK) ? W1 : W2;
  unsigned short* Wt = (b < NK) ? Wt1 : Wt2;
  const int k = (b < NK) ? b : b - NK;
  __shared__ unsigned short tile[128 * 130];
  const int t = threadIdx.x;
  for (int j = t; j < 16384; j += 256) {
    int ci = j >> 7, co = j & 127;
    tile[ci * 130 + co] = f2bf(W[(size_t)k * 16384 + j]);
  }
  __syncthreads();
  for (int j = t; j < 16384; j += 256) {
    int co = j >> 7, ci = j & 127;
    Wt[(size_t)k * 16384 + j] = tile[ci * 130 + co];
  }
}

// ---------------- BN1 stats: per-channel sum / sumsq of fp32 features ------------------
__global__ __launch_bounds__(256) void stats_kernel(const float* __restrict__ x,
                                                    float* __restrict__ ssum,
                                                    float* __restrict__ sssq) {
  const int t = threadIdx.x;
  const int c4 = (t & 31) * 4;
  const int rsub = t >> 5;  // 0..7
  const int rowend = blockIdx.x * 512 + 512;
  float s0 = 0, s1 = 0, s2 = 0, s3 = 0, q0 = 0, q1 = 0, q2 = 0, q3 = 0;
  for (int r = blockIdx.x * 512 + rsub; r < rowend; r += 8) {
    const float4 v = *(const float4*)&x[(size_t)r * 128 + c4];
    s0 += v.x; q0 += v.x * v.x;
    s1 += v.y; q1 += v.y * v.y;
    s2 += v.z; q2 += v.z * v.z;
    s3 += v.w; q3 += v.w * v.w;
  }
  __shared__ float red[256 * 8];
  red[t * 8 + 0] = s0; red[t * 8 + 1] = s1; red[t * 8 + 2] = s2; red[t * 8 + 3] = s3;
  red[t * 8 + 4] = q0; red[t * 8 + 5] = q1; red[t * 8 + 6] = q2; red[t * 8 + 7] = q3;
  __syncthreads();
  if (t < 32) {
    float a0 = 0, a1 = 0, a2 = 0, a3 = 0, b0 = 0, b1 = 0, b2 = 0, b3 = 0;
    for (int j = 0; j < 8; ++j) {
      const float* p = &red[(j * 32 + t) * 8];
      a0 += p[0]; a1 += p[1]; a2 += p[2]; a3 += p[3];
      b0 += p[4]; b1 += p[5]; b2 += p[6]; b3 += p[7];
    }
    atomicAdd(&ssum[t * 4 + 0], a0); atomicAdd(&ssum[t * 4 + 1], a1);
    atomicAdd(&ssum[t * 4 + 2], a2); atomicAdd(&ssum[t * 4 + 3], a3);
    atomicAdd(&sssq[t * 4 + 0], b0); atomicAdd(&sssq[t * 4 + 1], b1);
    atomicAdd(&sssq[t * 4 + 2], b2); atomicAdd(&sssq[t * 4 + 3], b3);
  }
}

// ---------------- BN+ReLU apply, fp32 input -> bf16 out (+ zero row NS) ----------------
__global__ __launch_bounds__(256) void apply_f32_kernel(const float* __restrict__ x,
    const float* __restrict__ ssum, const float* __restrict__ sssq,
    const float* __restrict__ gamma, const float* __restrict__ beta,
    unsigned short* __restrict__ hout) {
  const size_t base = ((size_t)blockIdx.x * 256 + threadIdx.x) * 8;
  const int c0 = (int)(base & 127);
  const float4 v0 = *(const float4*)&x[base];
  const float4 v1 = *(const float4*)&x[base + 4];
  const float vv[8] = {v0.x, v0.y, v0.z, v0.w, v1.x, v1.y, v1.z, v1.w};
  unsigned short o[8] __attribute__((aligned(16)));
  const float invN = 1.0f / (float)NS;
  #pragma unroll
  for (int j = 0; j < 8; ++j) {
    const int c = c0 + j;
    const float mean = ssum[c] * invN;
    const float var = sssq[c] * invN - mean * mean;
    const float sc = gamma[c] * rsqrtf(var + 1e-4f);
    const float t = (vv[j] - mean) * sc + beta[c];
    o[j] = f2bf(fmaxf(t, 0.0f));
  }
  *(int4*)&hout[base] = *(const int4*)o;
  if (blockIdx.x == 0 && threadIdx.x < 16) {
    int4 z; z.x = 0; z.y = 0; z.z = 0; z.w = 0;
    ((int4*)(hout + (size_t)NS * 128))[threadIdx.x] = z;  // zero sentinel row
  }
}

// ---------------- BN+ReLU apply, bf16 input -> bf16 out --------------------------------
__global__ __launch_bounds__(256) void apply_bf16_kernel(const unsigned short* __restrict__ x,
    const float* __restrict__ ssum, const float* __restrict__ sssq,
    const float* __restrict__ gamma, const float* __restrict__ beta,
    unsigned short* __restrict__ hout) {
  const size_t base = ((size_t)blockIdx.x * 256 + threadIdx.x) * 8;
  const int c0 = (int)(base & 127);
  unsigned short in[8] __attribute__((aligned(16)));
  *(int4*)in = *(const int4*)&x[base];
  unsigned short o[8] __attribute__((aligned(16)));
  const float invN = 1.0f / (float)NS;
  #pragma unroll
  for (int j = 0; j < 8; ++j) {
    const int c = c0 + j;
    const float mean = ssum[c] * invN;
    const float var = sssq[c] * invN - mean * mean;
    const float sc = gamma[c] * rsqrtf(var + 1e-4f);
    const float t = (bf2f(in[j]) - mean) * sc + beta[c];
    o[j] = f2bf(fmaxf(t, 0.0f));
  }
  *(int4*)&hout[base] = *(const int4*)o;
}

// ---------------- gathered-GEMM submanifold conv ---------------------------------------
// Champion staging structure for A (DMA + XOR-swizzled LDS, verified 0-conflict), but
// B (weights) is now read DIRECTLY global->VGPR: Wt is 885KB -> fully L2-resident and
// shared by all blocks, so staging it through LDS was pure overhead (m169 pattern:
// stage only what doesn't cache-fit). This halves LDS reads (16->8 b128/lane/half),
// halves barrier-coupled DMA (8->4), and shrinks LDS 32->16KB. B-fragment address:
//   Wt + k*16K + col*128 + half*64 + ks*32 + quad*8   (16B/lane, L2-hot)
// ks=1's B batch (bb*) is issued during ks=0's MFMAs to hide L2 latency; named
// batches keep peak live VGPRs ~160 (<170) so 3 blocks/CU is preserved.
template <bool FIRST>
__global__ __launch_bounds__(256, 3) void conv_kernel(
    const unsigned short* __restrict__ h,   // (NS+1) x 128 bf16, row NS = zeros
    const int* __restrict__ idx2t,          // [NK][NS]
    const unsigned short* __restrict__ Wt,  // [NK][128 cout][128 cin] bf16
    const float* __restrict__ bias,
    unsigned short* __restrict__ out_bf,    // FIRST: bf16 out
    float* __restrict__ ssum, float* __restrict__ sssq,  // FIRST: BN2 stats
    const float* __restrict__ resid,        // !FIRST: residual
    float* __restrict__ outf) {             // !FIRST: fp32 out
  __shared__ unsigned short A_lds[128 * 64];  // 16KB (A only)
  const int tid = threadIdx.x;
  const int wave = tid >> 6, lane = tid & 63;
  const int wm = wave >> 1, wn = wave & 1;
  const int i16 = lane & 15, quad = lane >> 4;
  const int lrow = lane >> 3, lch = lane & 7;
  const int sch = lch ^ lrow;  // swizzled global chunk for A staging
  const int sb = blockIdx.x << 7;
  // B per-lane element offset base: col*128 + quad*8, col = wn*64 + ni*16 + i16
  const int cB = ((wn * 64 + i16) << 7) + (quad << 3);

  f32x4 acc[4][4];
  #pragma unroll
  for (int a = 0; a < 4; ++a)
    #pragma unroll
    for (int b = 0; b < 4; ++b) { acc[a][b][0] = 0.f; acc[a][b][1] = 0.f; acc[a][b][2] = 0.f; acc[a][b][3] = 0.f; }

  for (int k = 0; k < NK; ++k) {
    int ridx[4];
    #pragma unroll
    for (int i = 0; i < 4; ++i)
      ridx[i] = idx2t[k * NS + sb + wave * 32 + i * 8 + lrow];
    #pragma unroll
    for (int half = 0; half < 2; ++half) {
      __syncthreads();
      // stage A only (4 DMAs; B no longer staged)
      #pragma unroll
      for (int i = 0; i < 4; ++i) {
        const unsigned short* ga =
            h + (((size_t)ridx[i]) << 7) + (half << 6) + (sch << 3);
        async16(ga, A_lds + ((wave * 4 + i) << 9));
      }
      // B direct loads, ks=0 batch (overlaps the DMA flight; drained by the barrier)
      const unsigned short* bk = Wt + (((size_t)k) << 14) + (half << 6);
      bf16x8 ba0 = *(const bf16x8*)(bk + cB);
      bf16x8 ba1 = *(const bf16x8*)(bk + cB + 2048);
      bf16x8 ba2 = *(const bf16x8*)(bk + cB + 4096);
      bf16x8 ba3 = *(const bf16x8*)(bk + cB + 6144);
      __syncthreads();
      // ks = 0: A fragments from LDS (chunk = quad ^ (i16&7) -> global chunk quad)
      {
        const int chunk = quad ^ (i16 & 7);
        bf16x8 af0 = *(const bf16x8*)&A_lds[((wm * 64 + 0 * 16 + i16) << 6) + (chunk << 3)];
        bf16x8 af1 = *(const bf16x8*)&A_lds[((wm * 64 + 1 * 16 + i16) << 6) + (chunk << 3)];
        bf16x8 af2 = *(const bf16x8*)&A_lds[((wm * 64 + 2 * 16 + i16) << 6) + (chunk << 3)];
        bf16x8 af3 = *(const bf16x8*)&A_lds[((wm * 64 + 3 * 16 + i16) << 6) + (chunk << 3)];
        // prefetch ks=1 B batch under ks=0 MFMAs
        bf16x8 bb0 = *(const bf16x8*)(bk + cB + 32);
        bf16x8 bb1 = *(const bf16x8*)(bk + cB + 2048 + 32);
        bf16x8 bb2 = *(const bf16x8*)(bk + cB + 4096 + 32);
        bf16x8 bb3 = *(const bf16x8*)(bk + cB + 6144 + 32);
        acc[0][0] = __builtin_amdgcn_mfma_f32_16x16x32_bf16(af0, ba0, acc[0][0], 0, 0, 0);
        acc[0][1] = __builtin_amdgcn_mfma_f32_16x16x32_bf16(af0, ba1, acc[0][1], 0, 0, 0);
        acc[0][2] = __builtin_amdgcn_mfma_f32_16x16x32_bf16(af0, ba2, acc[0][2], 0, 0, 0);
        acc[0][3] = __builtin_amdgcn_mfma_f32_16x16x32_bf16(af0, ba3, acc[0][3], 0, 0, 0);
        acc[1][0] = __builtin_amdgcn_mfma_f32_16x16x32_bf16(af1, ba0, acc[1][0], 0, 0, 0);
        acc[1][1] = __builtin_amdgcn_mfma_f32_16x16x32_bf16(af1, ba1, acc[1][1], 0, 0, 0);
        acc[1][2] = __builtin_amdgcn_mfma_f32_16x16x32_bf16(af1, ba2, acc[1][2], 0, 0, 0);
        acc[1][3] = __builtin_amdgcn_mfma_f32_16x16x32_bf16(af1, ba3, acc[1][3], 0, 0, 0);
        acc[2][0] = __builtin_amdgcn_mfma_f32_16x16x32_bf16(af2, ba0, acc[2][0], 0, 0, 0);
        acc[2][1] = __builtin_amdgcn_mfma_f32_16x16x32_bf16(af2, ba1, acc[2][1], 0, 0, 0);
        acc[2][2] = __builtin_amdgcn_mfma_f32_16x16x32_bf16(af2, ba2, acc[2][2], 0, 0, 0);
        acc[2][3] = __builtin_amdgcn_mfma_f32_16x16x32_bf16(af2, ba3, acc[2][3], 0, 0, 0);
        acc[3][0] = __builtin_amdgcn_mfma_f32_16x16x32_bf16(af3, ba0, acc[3][0], 0, 0, 0);
        acc[3][1] = __builtin_amdgcn_mfma_f32_16x16x32_bf16(af3, ba1, acc[3][1], 0, 0, 0);
        acc[3][2] = __builtin_amdgcn_mfma_f32_16x16x32_bf16(af3, ba2, acc[3][2], 0, 0, 0);
        acc[3][3] = __builtin_amdgcn_mfma_f32_16x16x32_bf16(af3, ba3, acc[3][3], 0, 0, 0);
        // ks = 1
        const int chunk1 = (4 + quad) ^ (i16 & 7);
        bf16x8 ag0 = *(const bf16x8*)&A_lds[((wm * 64 + 0 * 16 + i16) << 6) + (chunk1 << 3)];
        bf16x8 ag1 = *(const bf16x8*)&A_lds[((wm * 64 + 1 * 16 + i16) << 6) + (chunk1 << 3)];
        bf16x8 ag2 = *(const bf16x8*)&A_lds[((wm * 64 + 2 * 16 + i16) << 6) + (chunk1 << 3)];
        bf16x8 ag3 = *(const bf16x8*)&A_lds[((wm * 64 + 3 * 16 + i16) << 6) + (chunk1 << 3)];
        acc[0][0] = __builtin_amdgcn_mfma_f32_16x16x32_bf16(ag0, bb0, acc[0][0], 0, 0, 0);
        acc[0][1] = __builtin_amdgcn_mfma_f32_16x16x32_bf16(ag0, bb1, acc[0][1], 0, 0, 0);
        acc[0][2] = __builtin_amdgcn_mfma_f32_16x16x32_bf16(ag0, bb2, acc[0][2], 0, 0, 0);
        acc[0][3] = __builtin_amdgcn_mfma_f32_16x16x32_bf16(ag0, bb3, acc[0][3], 0, 0, 0);
        acc[1][0] = __builtin_amdgcn_mfma_f32_16x16x32_bf16(ag1, bb0, acc[1][0], 0, 0, 0);
        acc[1][1] = __builtin_amdgcn_mfma_f32_16x16x32_bf16(ag1, bb1, acc[1][1], 0, 0, 0);
        acc[1][2] = __builtin_amdgcn_mfma_f32_16x16x32_bf16(ag1, bb2, acc[1][2], 0, 0, 0);
        acc[1][3] = __builtin_amdgcn_mfma_f32_16x16x32_bf16(ag1, bb3, acc[1][3], 0, 0, 0);
        acc[2][0] = __builtin_amdgcn_mfma_f32_16x16x32_bf16(ag2, bb0, acc[2][0], 0, 0, 0);
        acc[2][1] = __builtin_amdgcn_mfma_f32_16x16x32_bf16(ag2, bb1, acc[2][1], 0, 0, 0);
        acc[2][2] = __builtin_amdgcn_mfma_f32_16x16x32_bf16(ag2, bb2, acc[2][2], 0, 0, 0);
        acc[2][3] = __builtin_amdgcn_mfma_f32_16x16x32_bf16(ag2, bb3, acc[2][3], 0, 0, 0);
        acc[3][0] = __builtin_amdgcn_mfma_f32_16x16x32_bf16(ag3, bb0, acc[3][0], 0, 0, 0);
        acc[3][1] = __builtin_amdgcn_mfma_f32_16x16x32_bf16(ag3, bb1, acc[3][1], 0, 0, 0);
        acc[3][2] = __builtin_amdgcn_mfma_f32_16x16x32_bf16(ag3, bb2, acc[3][2], 0, 0, 0);
        acc[3][3] = __builtin_amdgcn_mfma_f32_16x16x32_bf16(ag3, bb3, acc[3][3], 0, 0, 0);
      }
    }
  }

  if (FIRST) {
    float cs[4], cq[4];
    #pragma unroll
    for (int ni = 0; ni < 4; ++ni) {
      const int col = wn * 64 + ni * 16 + i16;
      const float bv = bias[col];
      float s = 0.f, q = 0.f;
      #pragma unroll
      for (int mi = 0; mi < 4; ++mi) {
        const int rowb = sb + wm * 64 + mi * 16 + quad * 4;
        #pragma unroll
        for (int i = 0; i < 4; ++i) {
          const float v = acc[mi][ni][i] + bv;
          out_bf[(size_t)(rowb + i) * 128 + col] = f2bf(v);
          s += v; q += v * v;
        }
      }
      cs[ni] = s; cq[ni] = q;
    }
    #pragma unroll
    for (int ni = 0; ni < 4; ++ni) {
      cs[ni] += __shfl_xor(cs[ni], 16); cs[ni] += __shfl_xor(cs[ni], 32);
      cq[ni] += __shfl_xor(cq[ni], 16); cq[ni] += __shfl_xor(cq[ni], 32);
    }
    __syncthreads();
    float* red = (float*)A_lds;
    if (wm == 1 && quad == 0) {
      #pragma unroll
      for (int ni = 0; ni < 4; ++ni) {
        const int col = wn * 64 + ni * 16 + i16;
        red[col] = cs[ni]; red[128 + col] = cq[ni];
      }
    }
    __syncthreads();
    if (wm == 0 && quad == 0) {
      #pragma unroll
      for (int ni = 0; ni < 4; ++ni) {
        const int col = wn * 64 + ni * 16 + i16;
        atomicAdd(&ssum[col], cs[ni] + red[col]);
        atomicAdd(&sssq[col], cq[ni] + red[128 + col]);
      }
    }
  } else {
    #pragma unroll
    for (int ni = 0; ni < 4; ++ni) {
      const int col = wn * 64 + ni * 16 + i16;
      const float bv = bias[col];
      #pragma unroll
      for (int mi = 0; mi < 4; ++mi) {
        const int rowb = sb + wm * 64 + mi * 16 + quad * 4;
        #pragma unroll
        for (int i = 0; i < 4; ++i) {
          const size_t o = (size_t)(rowb + i) * 128 + col;
          const float rv = __builtin_nontemporal_load(&resid[o]);
          __builtin_nontemporal_store(acc[mi][ni][i] + bv + rv, &outf[o]);
        }
      }
    }
  }
}

extern "C" void kernel_launch(void* const* d_in, const int* in_sizes, int n_in,
                              void* d_out, int out_size, void* d_ws, size_t ws_size,
                              hipStream_t stream) {
  const float* features = (const float*)d_in[0];
  const int* nbr_idx    = (const int*)d_in[1];
  const int* nbr_mask   = (const int*)d_in[2];
  const float* gamma1   = (const float*)d_in[3];
  const float* beta1    = (const float*)d_in[4];
  const float* W1       = (const float*)d_in[5];
  const float* bias1    = (const float*)d_in[6];
  const float* gamma2   = (const float*)d_in[7];
  const float* beta2    = (const float*)d_in[8];
  const float* W2       = (const float*)d_in[9];
  const float* bias2    = (const float*)d_in[10];

  char* ws = (char*)d_ws;
  size_t off = 0;
  unsigned short* h = (unsigned short*)(ws + off); off += (size_t)(NS + 1) * 128 * 2;
  unsigned short* out1 = (unsigned short*)(ws + off); off += (size_t)NS * 128 * 2;
  int* idx2t = (int*)(ws + off); off += (size_t)NK * NS * 4;
  unsigned short* Wt1 = (unsigned short*)(ws + off); off += (size_t)NK * 128 * 128 * 2;
  unsigned short* Wt2 = (unsigned short*)(ws + off); off += (size_t)NK * 128 * 128 * 2;
  float* stats = (float*)(ws + off); off += 4 * 128 * 4;
  float* sum1 = stats, *ssq1 = stats + 128, *sum2 = stats + 256, *ssq2 = stats + 384;

  hipMemsetAsync(stats, 0, 4 * 128 * 4, stream);
  prep_idx_kernel<<<NS / 256, 256, 0, stream>>>(nbr_idx, nbr_mask, idx2t);
  prep_w_kernel<<<2 * NK, 256, 0, stream>>>(W1, W2, Wt1, Wt2);
  stats_kernel<<<NS / 512, 256, 0, stream>>>(features, sum1, ssq1);
  apply_f32_kernel<<<(NS * 128) / 2048, 256, 0, stream>>>(features, sum1, ssq1, gamma1, beta1, h);
  conv_kernel<true><<<NS / 128, 256, 0, stream>>>(h, idx2t, Wt1, bias1, out1, sum2, ssq2, nullptr, nullptr);
  apply_bf16_kernel<<<(NS * 128) / 2048, 256, 0, stream>>>(out1, sum2, ssq2, gamma2, beta2, h);
  conv_kernel<false><<<NS / 128, 256, 0, stream>>>(h, idx2t, Wt2, bias2, nullptr, nullptr, nullptr,
                                                   features, (float*)d_out);
}

// Round 8
// 852.457 us; speedup vs baseline: 1.5885x; 1.5885x over previous
//
#include <hip/hip_runtime.h>

#define NS 262144
#define NK 27

typedef float f32x4 __attribute__((ext_vector_type(4)));
typedef __bf16 bf16x8 __attribute__((ext_vector_type(8)));

__device__ __forceinline__ unsigned short f2bf(float f) {
  union { float f; unsigned int i; } c; c.f = f;
  unsigned int r = c.i + 0x7fffu + ((c.i >> 16) & 1u);
  return (unsigned short)(r >> 16);
}
__device__ __forceinline__ float bf2f(unsigned short u) {
  union { unsigned int i; float f; } c; c.i = ((unsigned int)u) << 16;
  return c.f;
}
__device__ __forceinline__ void async16(const void* gp, void* lp) {
  __builtin_amdgcn_global_load_lds((const __attribute__((address_space(1))) void*)gp,
                                   (__attribute__((address_space(3))) void*)lp, 16, 0, 0);
}

// ---------------- fused prep: idx-transpose | weight-transpose | BN1 stats --------------
// Three mutually-independent prep workloads in ONE launch (they previously serialized
// as 3 stream-ordered kernels, paying 2 launch overheads + tail bubbles).
// blocks [0,1024): idx2t[k][site] = mask ? idx : NS
// blocks [1024,1078): W[k][cin][cout] fp32 -> Wt[k][cout][cin] bf16 (54 blocks)
// blocks [1078,1590): per-channel sum/sumsq of features (512 blocks x 512 rows)
// Shared memory unioned at 54KB (= prep_idx's existing footprint -> same 2 blocks/CU
// cap as before; stats ran at 2/CU anyway at 512 blocks).
__global__ __launch_bounds__(256) void fused_prep_kernel(
    const int* __restrict__ nidx, const int* __restrict__ nmask, int* __restrict__ idx2t,
    const float* __restrict__ W1, const float* __restrict__ W2,
    unsigned short* __restrict__ Wt1, unsigned short* __restrict__ Wt2,
    const float* __restrict__ x, float* __restrict__ ssum, float* __restrict__ sssq) {
  __shared__ __attribute__((aligned(16))) char smem[55296];
  const int bid = blockIdx.x;
  const int t = threadIdx.x;
  if (bid < 1024) {
    // ---- prep_idx ----
    int* li = (int*)smem;
    int* lm = (int*)(smem + 27648);
    const int sb = bid * 256;
    for (int j = t; j < 256 * NK; j += 256) {
      li[j] = nidx[(size_t)sb * NK + j];
      lm[j] = nmask[(size_t)sb * NK + j];
    }
    __syncthreads();
    for (int k = 0; k < NK; ++k) {
      int m = lm[t * NK + k];
      int v = li[t * NK + k];
      idx2t[(size_t)k * NS + sb + t] = m ? v : NS;
    }
  } else if (bid < 1078) {
    // ---- prep_w ----
    const int b = bid - 1024;  // 0..53
    const float* W = (b < NK) ? W1 : W2;
    unsigned short* Wt = (b < NK) ? Wt1 : Wt2;
    const int k = (b < NK) ? b : b - NK;
    unsigned short* tile = (unsigned short*)smem;  // 128*130*2 = 33280 B
    for (int j = t; j < 16384; j += 256) {
      int ci = j >> 7, co = j & 127;
      tile[ci * 130 + co] = f2bf(W[(size_t)k * 16384 + j]);
    }
    __syncthreads();
    for (int j = t; j < 16384; j += 256) {
      int co = j >> 7, ci = j & 127;
      Wt[(size_t)k * 16384 + j] = tile[ci * 130 + co];
    }
  } else {
    // ---- BN1 stats ----
    const int b = bid - 1078;  // 0..511
    const int c4 = (t & 31) * 4;
    const int rsub = t >> 5;  // 0..7
    const int rowend = b * 512 + 512;
    float s0 = 0, s1 = 0, s2 = 0, s3 = 0, q0 = 0, q1 = 0, q2 = 0, q3 = 0;
    for (int r = b * 512 + rsub; r < rowend; r += 8) {
      const float4 v = *(const float4*)&x[(size_t)r * 128 + c4];
      s0 += v.x; q0 += v.x * v.x;
      s1 += v.y; q1 += v.y * v.y;
      s2 += v.z; q2 += v.z * v.z;
      s3 += v.w; q3 += v.w * v.w;
    }
    float* red = (float*)smem;  // 256*8*4 = 8192 B
    red[t * 8 + 0] = s0; red[t * 8 + 1] = s1; red[t * 8 + 2] = s2; red[t * 8 + 3] = s3;
    red[t * 8 + 4] = q0; red[t * 8 + 5] = q1; red[t * 8 + 6] = q2; red[t * 8 + 7] = q3;
    __syncthreads();
    if (t < 32) {
      float a0 = 0, a1 = 0, a2 = 0, a3 = 0, b0 = 0, b1 = 0, b2 = 0, b3 = 0;
      for (int j = 0; j < 8; ++j) {
        const float* p = &red[(j * 32 + t) * 8];
        a0 += p[0]; a1 += p[1]; a2 += p[2]; a3 += p[3];
        b0 += p[4]; b1 += p[5]; b2 += p[6]; b3 += p[7];
      }
      atomicAdd(&ssum[t * 4 + 0], a0); atomicAdd(&ssum[t * 4 + 1], a1);
      atomicAdd(&ssum[t * 4 + 2], a2); atomicAdd(&ssum[t * 4 + 3], a3);
      atomicAdd(&sssq[t * 4 + 0], b0); atomicAdd(&sssq[t * 4 + 1], b1);
      atomicAdd(&sssq[t * 4 + 2], b2); atomicAdd(&sssq[t * 4 + 3], b3);
    }
  }
}

// ---------------- BN+ReLU apply, fp32 input -> bf16 out (+ zero row NS) ----------------
__global__ __launch_bounds__(256) void apply_f32_kernel(const float* __restrict__ x,
    const float* __restrict__ ssum, const float* __restrict__ sssq,
    const float* __restrict__ gamma, const float* __restrict__ beta,
    unsigned short* __restrict__ hout) {
  const size_t base = ((size_t)blockIdx.x * 256 + threadIdx.x) * 8;
  const int c0 = (int)(base & 127);
  const float4 v0 = *(const float4*)&x[base];
  const float4 v1 = *(const float4*)&x[base + 4];
  const float vv[8] = {v0.x, v0.y, v0.z, v0.w, v1.x, v1.y, v1.z, v1.w};
  unsigned short o[8] __attribute__((aligned(16)));
  const float invN = 1.0f / (float)NS;
  #pragma unroll
  for (int j = 0; j < 8; ++j) {
    const int c = c0 + j;
    const float mean = ssum[c] * invN;
    const float var = sssq[c] * invN - mean * mean;
    const float sc = gamma[c] * rsqrtf(var + 1e-4f);
    const float t = (vv[j] - mean) * sc + beta[c];
    o[j] = f2bf(fmaxf(t, 0.0f));
  }
  *(int4*)&hout[base] = *(const int4*)o;
  if (blockIdx.x == 0 && threadIdx.x < 16) {
    int4 z; z.x = 0; z.y = 0; z.z = 0; z.w = 0;
    ((int4*)(hout + (size_t)NS * 128))[threadIdx.x] = z;  // zero sentinel row
  }
}

// ---------------- BN+ReLU apply, bf16 input -> bf16 out --------------------------------
__global__ __launch_bounds__(256) void apply_bf16_kernel(const unsigned short* __restrict__ x,
    const float* __restrict__ ssum, const float* __restrict__ sssq,
    const float* __restrict__ gamma, const float* __restrict__ beta,
    unsigned short* __restrict__ hout) {
  const size_t base = ((size_t)blockIdx.x * 256 + threadIdx.x) * 8;
  const int c0 = (int)(base & 127);
  unsigned short in[8] __attribute__((aligned(16)));
  *(int4*)in = *(const int4*)&x[base];
  unsigned short o[8] __attribute__((aligned(16)));
  const float invN = 1.0f / (float)NS;
  #pragma unroll
  for (int j = 0; j < 8; ++j) {
    const int c = c0 + j;
    const float mean = ssum[c] * invN;
    const float var = sssq[c] * invN - mean * mean;
    const float sc = gamma[c] * rsqrtf(var + 1e-4f);
    const float t = (bf2f(in[j]) - mean) * sc + beta[c];
    o[j] = f2bf(fmaxf(t, 0.0f));
  }
  *(int4*)&hout[base] = *(const int4*)o;
}

// ---------------- gathered-GEMM submanifold conv ---------------------------------------
// Champion structure (best session conv: 272-274us): 128 sites x 128 cout per block;
// 27 offsets x 2 cin-halves; A+B DMA-staged to XOR-swizzled LDS; 32KB -> 3 blocks/CU;
// nontemporal resid/outf epilogue (R6: small real win, kept).
// Refuted alternatives (R1-R4,R7): depth-1 dbuf, depth-2 counted-vmcnt (2 forms),
// zero-LDS register-direct, B-direct-from-L2. This is the empirical optimum.
template <bool FIRST>
__global__ __launch_bounds__(256, 3) void conv_kernel(
    const unsigned short* __restrict__ h,   // (NS+1) x 128 bf16, row NS = zeros
    const int* __restrict__ idx2t,          // [NK][NS]
    const unsigned short* __restrict__ Wt,  // [NK][128 cout][128 cin] bf16
    const float* __restrict__ bias,
    unsigned short* __restrict__ out_bf,    // FIRST: bf16 out
    float* __restrict__ ssum, float* __restrict__ sssq,  // FIRST: BN2 stats
    const float* __restrict__ resid,        // !FIRST: residual
    float* __restrict__ outf) {             // !FIRST: fp32 out
  __shared__ unsigned short A_lds[128 * 64];
  __shared__ unsigned short B_lds[128 * 64];
  const int tid = threadIdx.x;
  const int wave = tid >> 6, lane = tid & 63;
  const int wm = wave >> 1, wn = wave & 1;
  const int i16 = lane & 15, quad = lane >> 4;
  const int lrow = lane >> 3, lch = lane & 7;
  const int sch = lch ^ lrow;  // swizzled global chunk for staging
  const int sb = blockIdx.x << 7;

  f32x4 acc[4][4];
  #pragma unroll
  for (int a = 0; a < 4; ++a)
    #pragma unroll
    for (int b = 0; b < 4; ++b) { acc[a][b][0] = 0.f; acc[a][b][1] = 0.f; acc[a][b][2] = 0.f; acc[a][b][3] = 0.f; }

  for (int k = 0; k < NK; ++k) {
    int ridx[4];
    #pragma unroll
    for (int i = 0; i < 4; ++i)
      ridx[i] = idx2t[k * NS + sb + wave * 32 + i * 8 + lrow];
    #pragma unroll
    for (int half = 0; half < 2; ++half) {
      __syncthreads();
      #pragma unroll
      for (int i = 0; i < 4; ++i) {
        const unsigned short* gb =
            Wt + (((size_t)k << 14) + ((wave * 32 + i * 8 + lrow) << 7) + (half << 6) + (sch << 3));
        async16(gb, B_lds + ((wave * 4 + i) << 9));
        const unsigned short* ga =
            h + (((size_t)ridx[i]) << 7) + (half << 6) + (sch << 3);
        async16(ga, A_lds + ((wave * 4 + i) << 9));
      }
      __syncthreads();
      #pragma unroll
      for (int ks = 0; ks < 2; ++ks) {
        const int chunk = (ks * 4 + quad) ^ (i16 & 7);
        bf16x8 af[4], bfr[4];
        #pragma unroll
        for (int mi = 0; mi < 4; ++mi)
          af[mi] = *(const bf16x8*)&A_lds[((wm * 64 + mi * 16 + i16) << 6) + (chunk << 3)];
        #pragma unroll
        for (int ni = 0; ni < 4; ++ni)
          bfr[ni] = *(const bf16x8*)&B_lds[((wn * 64 + ni * 16 + i16) << 6) + (chunk << 3)];
        #pragma unroll
        for (int mi = 0; mi < 4; ++mi)
          #pragma unroll
          for (int ni = 0; ni < 4; ++ni)
            acc[mi][ni] = __builtin_amdgcn_mfma_f32_16x16x32_bf16(af[mi], bfr[ni], acc[mi][ni], 0, 0, 0);
      }
    }
  }

  if (FIRST) {
    float cs[4], cq[4];
    #pragma unroll
    for (int ni = 0; ni < 4; ++ni) {
      const int col = wn * 64 + ni * 16 + i16;
      const float bv = bias[col];
      float s = 0.f, q = 0.f;
      #pragma unroll
      for (int mi = 0; mi < 4; ++mi) {
        const int rowb = sb + wm * 64 + mi * 16 + quad * 4;
        #pragma unroll
        for (int i = 0; i < 4; ++i) {
          const float v = acc[mi][ni][i] + bv;
          out_bf[(size_t)(rowb + i) * 128 + col] = f2bf(v);
          s += v; q += v * v;
        }
      }
      cs[ni] = s; cq[ni] = q;
    }
    #pragma unroll
    for (int ni = 0; ni < 4; ++ni) {
      cs[ni] += __shfl_xor(cs[ni], 16); cs[ni] += __shfl_xor(cs[ni], 32);
      cq[ni] += __shfl_xor(cq[ni], 16); cq[ni] += __shfl_xor(cq[ni], 32);
    }
    __syncthreads();
    float* red = (float*)A_lds;
    if (wm == 1 && quad == 0) {
      #pragma unroll
      for (int ni = 0; ni < 4; ++ni) {
        const int col = wn * 64 + ni * 16 + i16;
        red[col] = cs[ni]; red[128 + col] = cq[ni];
      }
    }
    __syncthreads();
    if (wm == 0 && quad == 0) {
      #pragma unroll
      for (int ni = 0; ni < 4; ++ni) {
        const int col = wn * 64 + ni * 16 + i16;
        atomicAdd(&ssum[col], cs[ni] + red[col]);
        atomicAdd(&sssq[col], cq[ni] + red[128 + col]);
      }
    }
  } else {
    #pragma unroll
    for (int ni = 0; ni < 4; ++ni) {
      const int col = wn * 64 + ni * 16 + i16;
      const float bv = bias[col];
      #pragma unroll
      for (int mi = 0; mi < 4; ++mi) {
        const int rowb = sb + wm * 64 + mi * 16 + quad * 4;
        #pragma unroll
        for (int i = 0; i < 4; ++i) {
          const size_t o = (size_t)(rowb + i) * 128 + col;
          const float rv = __builtin_nontemporal_load(&resid[o]);
          __builtin_nontemporal_store(acc[mi][ni][i] + bv + rv, &outf[o]);
        }
      }
    }
  }
}

extern "C" void kernel_launch(void* const* d_in, const int* in_sizes, int n_in,
                              void* d_out, int out_size, void* d_ws, size_t ws_size,
                              hipStream_t stream) {
  const float* features = (const float*)d_in[0];
  const int* nbr_idx    = (const int*)d_in[1];
  const int* nbr_mask   = (const int*)d_in[2];
  const float* gamma1   = (const float*)d_in[3];
  const float* beta1    = (const float*)d_in[4];
  const float* W1       = (const float*)d_in[5];
  const float* bias1    = (const float*)d_in[6];
  const float* gamma2   = (const float*)d_in[7];
  const float* beta2    = (const float*)d_in[8];
  const float* W2       = (const float*)d_in[9];
  const float* bias2    = (const float*)d_in[10];

  char* ws = (char*)d_ws;
  size_t off = 0;
  unsigned short* h = (unsigned short*)(ws + off); off += (size_t)(NS + 1) * 128 * 2;
  unsigned short* out1 = (unsigned short*)(ws + off); off += (size_t)NS * 128 * 2;
  int* idx2t = (int*)(ws + off); off += (size_t)NK * NS * 4;
  unsigned short* Wt1 = (unsigned short*)(ws + off); off += (size_t)NK * 128 * 128 * 2;
  unsigned short* Wt2 = (unsigned short*)(ws + off); off += (size_t)NK * 128 * 128 * 2;
  float* stats = (float*)(ws + off); off += 4 * 128 * 4;
  float* sum1 = stats, *ssq1 = stats + 128, *sum2 = stats + 256, *ssq2 = stats + 384;

  hipMemsetAsync(stats, 0, 4 * 128 * 4, stream);
  fused_prep_kernel<<<1590, 256, 0, stream>>>(nbr_idx, nbr_mask, idx2t, W1, W2, Wt1, Wt2,
                                              features, sum1, ssq1);
  apply_f32_kernel<<<(NS * 128) / 2048, 256, 0, stream>>>(features, sum1, ssq1, gamma1, beta1, h);
  conv_kernel<true><<<NS / 128, 256, 0, stream>>>(h, idx2t, Wt1, bias1, out1, sum2, ssq2, nullptr, nullptr);
  apply_bf16_kernel<<<(NS * 128) / 2048, 256, 0, stream>>>(out1, sum2, ssq2, gamma2, beta2, h);
  conv_kernel<false><<<NS / 128, 256, 0, stream>>>(h, idx2t, Wt2, bias2, nullptr, nullptr, nullptr,
                                                   features, (float*)d_out);
}

// Round 9
// 850.024 us; speedup vs baseline: 1.5930x; 1.0029x over previous
//
#include <hip/hip_runtime.h>

#define NS 262144
#define NK 27

typedef float f32x4 __attribute__((ext_vector_type(4)));
typedef __bf16 bf16x8 __attribute__((ext_vector_type(8)));

__device__ __forceinline__ unsigned short f2bf(float f) {
  union { float f; unsigned int i; } c; c.f = f;
  unsigned int r = c.i + 0x7fffu + ((c.i >> 16) & 1u);
  return (unsigned short)(r >> 16);
}
__device__ __forceinline__ float bf2f(unsigned short u) {
  union { unsigned int i; float f; } c; c.i = ((unsigned int)u) << 16;
  return c.f;
}
__device__ __forceinline__ void async16(const void* gp, void* lp) {
  __builtin_amdgcn_global_load_lds((const __attribute__((address_space(1))) void*)gp,
                                   (__attribute__((address_space(3))) void*)lp, 16, 0, 0);
}

// ---------------- fused prep: idx-transpose | weight-transpose | BN1 stats --------------
// blocks [0,1024): idx2t[k][site] = mask ? idx : NS
// blocks [1024,1078): W[k][cin][cout] fp32 -> Wt[k][cout][cin] bf16 (54 blocks)
// blocks [1078,1590): per-channel sum/sumsq of features (512 blocks x 512 rows)
__global__ __launch_bounds__(256) void fused_prep_kernel(
    const int* __restrict__ nidx, const int* __restrict__ nmask, int* __restrict__ idx2t,
    const float* __restrict__ W1, const float* __restrict__ W2,
    unsigned short* __restrict__ Wt1, unsigned short* __restrict__ Wt2,
    const float* __restrict__ x, float* __restrict__ ssum, float* __restrict__ sssq) {
  __shared__ __attribute__((aligned(16))) char smem[55296];
  const int bid = blockIdx.x;
  const int t = threadIdx.x;
  if (bid < 1024) {
    // ---- prep_idx ----
    int* li = (int*)smem;
    int* lm = (int*)(smem + 27648);
    const int sb = bid * 256;
    for (int j = t; j < 256 * NK; j += 256) {
      li[j] = nidx[(size_t)sb * NK + j];
      lm[j] = nmask[(size_t)sb * NK + j];
    }
    __syncthreads();
    for (int k = 0; k < NK; ++k) {
      int m = lm[t * NK + k];
      int v = li[t * NK + k];
      idx2t[(size_t)k * NS + sb + t] = m ? v : NS;
    }
  } else if (bid < 1078) {
    // ---- prep_w ----
    const int b = bid - 1024;  // 0..53
    const float* W = (b < NK) ? W1 : W2;
    unsigned short* Wt = (b < NK) ? Wt1 : Wt2;
    const int k = (b < NK) ? b : b - NK;
    unsigned short* tile = (unsigned short*)smem;  // 128*130*2 = 33280 B
    for (int j = t; j < 16384; j += 256) {
      int ci = j >> 7, co = j & 127;
      tile[ci * 130 + co] = f2bf(W[(size_t)k * 16384 + j]);
    }
    __syncthreads();
    for (int j = t; j < 16384; j += 256) {
      int co = j >> 7, ci = j & 127;
      Wt[(size_t)k * 16384 + j] = tile[ci * 130 + co];
    }
  } else {
    // ---- BN1 stats ----
    const int b = bid - 1078;  // 0..511
    const int c4 = (t & 31) * 4;
    const int rsub = t >> 5;  // 0..7
    const int rowend = b * 512 + 512;
    float s0 = 0, s1 = 0, s2 = 0, s3 = 0, q0 = 0, q1 = 0, q2 = 0, q3 = 0;
    for (int r = b * 512 + rsub; r < rowend; r += 8) {
      const float4 v = *(const float4*)&x[(size_t)r * 128 + c4];
      s0 += v.x; q0 += v.x * v.x;
      s1 += v.y; q1 += v.y * v.y;
      s2 += v.z; q2 += v.z * v.z;
      s3 += v.w; q3 += v.w * v.w;
    }
    float* red = (float*)smem;  // 256*8*4 = 8192 B
    red[t * 8 + 0] = s0; red[t * 8 + 1] = s1; red[t * 8 + 2] = s2; red[t * 8 + 3] = s3;
    red[t * 8 + 4] = q0; red[t * 8 + 5] = q1; red[t * 8 + 6] = q2; red[t * 8 + 7] = q3;
    __syncthreads();
    if (t < 32) {
      float a0 = 0, a1 = 0, a2 = 0, a3 = 0, b0 = 0, b1 = 0, b2 = 0, b3 = 0;
      for (int j = 0; j < 8; ++j) {
        const float* p = &red[(j * 32 + t) * 8];
        a0 += p[0]; a1 += p[1]; a2 += p[2]; a3 += p[3];
        b0 += p[4]; b1 += p[5]; b2 += p[6]; b3 += p[7];
      }
      atomicAdd(&ssum[t * 4 + 0], a0); atomicAdd(&ssum[t * 4 + 1], a1);
      atomicAdd(&ssum[t * 4 + 2], a2); atomicAdd(&ssum[t * 4 + 3], a3);
      atomicAdd(&sssq[t * 4 + 0], b0); atomicAdd(&sssq[t * 4 + 1], b1);
      atomicAdd(&sssq[t * 4 + 2], b2); atomicAdd(&sssq[t * 4 + 3], b3);
    }
  }
}

// ---------------- BN coefficient precompute: scale/shift per channel -------------------
// Collapses per-thread {32 scalar loads + 8 rsqrt} in the applies to 4 vector loads.
// y = (x - mean)*sc + beta  ==  x*scale + shift,  scale = gamma*rsqrt(var+eps),
// shift = beta - mean*scale.
__global__ __launch_bounds__(128) void bn_coef_kernel(const float* __restrict__ ssum,
    const float* __restrict__ sssq, const float* __restrict__ gamma,
    const float* __restrict__ beta, float* __restrict__ scale, float* __restrict__ shift) {
  const int c = threadIdx.x;  // 128 channels, 1 block
  const float invN = 1.0f / (float)NS;
  const float mean = ssum[c] * invN;
  const float var = sssq[c] * invN - mean * mean;
  const float sc = gamma[c] * rsqrtf(var + 1e-4f);
  scale[c] = sc;
  shift[c] = beta[c] - mean * sc;
}

// ---------------- BN+ReLU apply, fp32 input -> bf16 out (+ zero row NS) ----------------
__global__ __launch_bounds__(256) void apply_f32_kernel(const float* __restrict__ x,
    const float* __restrict__ scale, const float* __restrict__ shift,
    unsigned short* __restrict__ hout) {
  const size_t base = ((size_t)blockIdx.x * 256 + threadIdx.x) * 8;
  const int c0 = (int)(base & 127);
  const float4 v0 = *(const float4*)&x[base];
  const float4 v1 = *(const float4*)&x[base + 4];
  const float4 sA = *(const float4*)&scale[c0];
  const float4 sB = *(const float4*)&scale[c0 + 4];
  const float4 hA = *(const float4*)&shift[c0];
  const float4 hB = *(const float4*)&shift[c0 + 4];
  const float vv[8] = {v0.x, v0.y, v0.z, v0.w, v1.x, v1.y, v1.z, v1.w};
  const float sc[8] = {sA.x, sA.y, sA.z, sA.w, sB.x, sB.y, sB.z, sB.w};
  const float sh[8] = {hA.x, hA.y, hA.z, hA.w, hB.x, hB.y, hB.z, hB.w};
  unsigned short o[8] __attribute__((aligned(16)));
  #pragma unroll
  for (int j = 0; j < 8; ++j)
    o[j] = f2bf(fmaxf(fmaf(vv[j], sc[j], sh[j]), 0.0f));
  *(int4*)&hout[base] = *(const int4*)o;
  if (blockIdx.x == 0 && threadIdx.x < 16) {
    int4 z; z.x = 0; z.y = 0; z.z = 0; z.w = 0;
    ((int4*)(hout + (size_t)NS * 128))[threadIdx.x] = z;  // zero sentinel row
  }
}

// ---------------- BN+ReLU apply, bf16 input -> bf16 out --------------------------------
__global__ __launch_bounds__(256) void apply_bf16_kernel(const unsigned short* __restrict__ x,
    const float* __restrict__ scale, const float* __restrict__ shift,
    unsigned short* __restrict__ hout) {
  const size_t base = ((size_t)blockIdx.x * 256 + threadIdx.x) * 8;
  const int c0 = (int)(base & 127);
  unsigned short in[8] __attribute__((aligned(16)));
  *(int4*)in = *(const int4*)&x[base];
  const float4 sA = *(const float4*)&scale[c0];
  const float4 sB = *(const float4*)&scale[c0 + 4];
  const float4 hA = *(const float4*)&shift[c0];
  const float4 hB = *(const float4*)&shift[c0 + 4];
  const float sc[8] = {sA.x, sA.y, sA.z, sA.w, sB.x, sB.y, sB.z, sB.w};
  const float sh[8] = {hA.x, hA.y, hA.z, hA.w, hB.x, hB.y, hB.z, hB.w};
  unsigned short o[8] __attribute__((aligned(16)));
  #pragma unroll
  for (int j = 0; j < 8; ++j)
    o[j] = f2bf(fmaxf(fmaf(bf2f(in[j]), sc[j], sh[j]), 0.0f));
  *(int4*)&hout[base] = *(const int4*)o;
}

// ---------------- gathered-GEMM submanifold conv ---------------------------------------
// Champion structure (session best conv: 270.9-273.4us): 128 sites x 128 cout per block;
// 27 offsets x 2 cin-halves; A+B DMA-staged to XOR-swizzled LDS; 32KB -> 3 blocks/CU;
// nontemporal resid/outf epilogue. Refuted alternatives (R1-R4,R7): depth-1 dbuf,
// depth-2 counted-vmcnt (2 forms), zero-LDS register-direct, B-direct-from-L2.
template <bool FIRST>
__global__ __launch_bounds__(256, 3) void conv_kernel(
    const unsigned short* __restrict__ h,   // (NS+1) x 128 bf16, row NS = zeros
    const int* __restrict__ idx2t,          // [NK][NS]
    const unsigned short* __restrict__ Wt,  // [NK][128 cout][128 cin] bf16
    const float* __restrict__ bias,
    unsigned short* __restrict__ out_bf,    // FIRST: bf16 out
    float* __restrict__ ssum, float* __restrict__ sssq,  // FIRST: BN2 stats
    const float* __restrict__ resid,        // !FIRST: residual
    float* __restrict__ outf) {             // !FIRST: fp32 out
  __shared__ unsigned short A_lds[128 * 64];
  __shared__ unsigned short B_lds[128 * 64];
  const int tid = threadIdx.x;
  const int wave = tid >> 6, lane = tid & 63;
  const int wm = wave >> 1, wn = wave & 1;
  const int i16 = lane & 15, quad = lane >> 4;
  const int lrow = lane >> 3, lch = lane & 7;
  const int sch = lch ^ lrow;  // swizzled global chunk for staging
  const int sb = blockIdx.x << 7;

  f32x4 acc[4][4];
  #pragma unroll
  for (int a = 0; a < 4; ++a)
    #pragma unroll
    for (int b = 0; b < 4; ++b) { acc[a][b][0] = 0.f; acc[a][b][1] = 0.f; acc[a][b][2] = 0.f; acc[a][b][3] = 0.f; }

  for (int k = 0; k < NK; ++k) {
    int ridx[4];
    #pragma unroll
    for (int i = 0; i < 4; ++i)
      ridx[i] = idx2t[k * NS + sb + wave * 32 + i * 8 + lrow];
    #pragma unroll
    for (int half = 0; half < 2; ++half) {
      __syncthreads();
      #pragma unroll
      for (int i = 0; i < 4; ++i) {
        const unsigned short* gb =
            Wt + (((size_t)k << 14) + ((wave * 32 + i * 8 + lrow) << 7) + (half << 6) + (sch << 3));
        async16(gb, B_lds + ((wave * 4 + i) << 9));
        const unsigned short* ga =
            h + (((size_t)ridx[i]) << 7) + (half << 6) + (sch << 3);
        async16(ga, A_lds + ((wave * 4 + i) << 9));
      }
      __syncthreads();
      #pragma unroll
      for (int ks = 0; ks < 2; ++ks) {
        const int chunk = (ks * 4 + quad) ^ (i16 & 7);
        bf16x8 af[4], bfr[4];
        #pragma unroll
        for (int mi = 0; mi < 4; ++mi)
          af[mi] = *(const bf16x8*)&A_lds[((wm * 64 + mi * 16 + i16) << 6) + (chunk << 3)];
        #pragma unroll
        for (int ni = 0; ni < 4; ++ni)
          bfr[ni] = *(const bf16x8*)&B_lds[((wn * 64 + ni * 16 + i16) << 6) + (chunk << 3)];
        #pragma unroll
        for (int mi = 0; mi < 4; ++mi)
          #pragma unroll
          for (int ni = 0; ni < 4; ++ni)
            acc[mi][ni] = __builtin_amdgcn_mfma_f32_16x16x32_bf16(af[mi], bfr[ni], acc[mi][ni], 0, 0, 0);
      }
    }
  }

  if (FIRST) {
    float cs[4], cq[4];
    #pragma unroll
    for (int ni = 0; ni < 4; ++ni) {
      const int col = wn * 64 + ni * 16 + i16;
      const float bv = bias[col];
      float s = 0.f, q = 0.f;
      #pragma unroll
      for (int mi = 0; mi < 4; ++mi) {
        const int rowb = sb + wm * 64 + mi * 16 + quad * 4;
        #pragma unroll
        for (int i = 0; i < 4; ++i) {
          const float v = acc[mi][ni][i] + bv;
          out_bf[(size_t)(rowb + i) * 128 + col] = f2bf(v);
          s += v; q += v * v;
        }
      }
      cs[ni] = s; cq[ni] = q;
    }
    #pragma unroll
    for (int ni = 0; ni < 4; ++ni) {
      cs[ni] += __shfl_xor(cs[ni], 16); cs[ni] += __shfl_xor(cs[ni], 32);
      cq[ni] += __shfl_xor(cq[ni], 16); cq[ni] += __shfl_xor(cq[ni], 32);
    }
    __syncthreads();
    float* red = (float*)A_lds;
    if (wm == 1 && quad == 0) {
      #pragma unroll
      for (int ni = 0; ni < 4; ++ni) {
        const int col = wn * 64 + ni * 16 + i16;
        red[col] = cs[ni]; red[128 + col] = cq[ni];
      }
    }
    __syncthreads();
    if (wm == 0 && quad == 0) {
      #pragma unroll
      for (int ni = 0; ni < 4; ++ni) {
        const int col = wn * 64 + ni * 16 + i16;
        atomicAdd(&ssum[col], cs[ni] + red[col]);
        atomicAdd(&sssq[col], cq[ni] + red[128 + col]);
      }
    }
  } else {
    #pragma unroll
    for (int ni = 0; ni < 4; ++ni) {
      const int col = wn * 64 + ni * 16 + i16;
      const float bv = bias[col];
      #pragma unroll
      for (int mi = 0; mi < 4; ++mi) {
        const int rowb = sb + wm * 64 + mi * 16 + quad * 4;
        #pragma unroll
        for (int i = 0; i < 4; ++i) {
          const size_t o = (size_t)(rowb + i) * 128 + col;
          const float rv = __builtin_nontemporal_load(&resid[o]);
          __builtin_nontemporal_store(acc[mi][ni][i] + bv + rv, &outf[o]);
        }
      }
    }
  }
}

extern "C" void kernel_launch(void* const* d_in, const int* in_sizes, int n_in,
                              void* d_out, int out_size, void* d_ws, size_t ws_size,
                              hipStream_t stream) {
  const float* features = (const float*)d_in[0];
  const int* nbr_idx    = (const int*)d_in[1];
  const int* nbr_mask   = (const int*)d_in[2];
  const float* gamma1   = (const float*)d_in[3];
  const float* beta1    = (const float*)d_in[4];
  const float* W1       = (const float*)d_in[5];
  const float* bias1    = (const float*)d_in[6];
  const float* gamma2   = (const float*)d_in[7];
  const float* beta2    = (const float*)d_in[8];
  const float* W2       = (const float*)d_in[9];
  const float* bias2    = (const float*)d_in[10];

  char* ws = (char*)d_ws;
  size_t off = 0;
  unsigned short* h = (unsigned short*)(ws + off); off += (size_t)(NS + 1) * 128 * 2;
  unsigned short* out1 = (unsigned short*)(ws + off); off += (size_t)NS * 128 * 2;
  int* idx2t = (int*)(ws + off); off += (size_t)NK * NS * 4;
  unsigned short* Wt1 = (unsigned short*)(ws + off); off += (size_t)NK * 128 * 128 * 2;
  unsigned short* Wt2 = (unsigned short*)(ws + off); off += (size_t)NK * 128 * 128 * 2;
  float* stats = (float*)(ws + off); off += 4 * 128 * 4;
  float* coefs = (float*)(ws + off); off += 4 * 128 * 4;
  float* sum1 = stats, *ssq1 = stats + 128, *sum2 = stats + 256, *ssq2 = stats + 384;
  float* scale1 = coefs, *shift1 = coefs + 128, *scale2 = coefs + 256, *shift2 = coefs + 384;

  hipMemsetAsync(stats, 0, 4 * 128 * 4, stream);
  fused_prep_kernel<<<1590, 256, 0, stream>>>(nbr_idx, nbr_mask, idx2t, W1, W2, Wt1, Wt2,
                                              features, sum1, ssq1);
  bn_coef_kernel<<<1, 128, 0, stream>>>(sum1, ssq1, gamma1, beta1, scale1, shift1);
  apply_f32_kernel<<<(NS * 128) / 2048, 256, 0, stream>>>(features, scale1, shift1, h);
  conv_kernel<true><<<NS / 128, 256, 0, stream>>>(h, idx2t, Wt1, bias1, out1, sum2, ssq2, nullptr, nullptr);
  bn_coef_kernel<<<1, 128, 0, stream>>>(sum2, ssq2, gamma2, beta2, scale2, shift2);
  apply_bf16_kernel<<<(NS * 128) / 2048, 256, 0, stream>>>(out1, scale2, shift2, h);
  conv_kernel<false><<<NS / 128, 256, 0, stream>>>(h, idx2t, Wt2, bias2, nullptr, nullptr, nullptr,
                                                   features, (float*)d_out);
}